// Round 26
// baseline (190.011 us; speedup 1.0000x reference)
//
#include <hip/hip_runtime.h>
#include <hip/hip_bf16.h>

typedef unsigned short u16;
typedef unsigned int u32;
typedef __attribute__((ext_vector_type(8))) short short8;   // 8 bf16 (4 VGPRs)
typedef __attribute__((ext_vector_type(4))) float f32x4;

#define NTOK 740
#define NTMP 256
#define NTGT 484
#define DM   512
#define MH   8
#define MROWS 11840   // B*NTOK = 16*740
#define KPAD 768
#define LOG2E 1.4426950408889634f

__device__ __forceinline__ float b2f(u16 u) {
    union { unsigned int i; float f; } x; x.i = ((unsigned int)u) << 16; return x.f;
}
__device__ __forceinline__ u16 f2b(float f) {
    union { float f; unsigned int i; } x; x.f = f;
    unsigned int r = x.i + 0x7FFFu + ((x.i >> 16) & 1u);   // RNE
    return (u16)(r >> 16);
}
__device__ __forceinline__ u32 pk2(float a, float b) {
    union { __hip_bfloat162 h; u32 u; } p;
    p.h = __float22bfloat162_rn(float2{a, b});
    return p.u;
}
__device__ __forceinline__ float fexp2(float x) {   // raw v_exp_f32 (log2 domain)
    return __builtin_amdgcn_exp2f(x);
}
struct alignas(8) us4 { u16 x, y, z, w; };

__device__ __forceinline__ void gload16(const void* g, void* l) {
    __builtin_amdgcn_global_load_lds(
        (const __attribute__((address_space(1))) void*)g,
        (__attribute__((address_space(3))) void*)l, 16, 0, 0);
}

// -------- merged prologue: weight transposes + conv-weight fold + bias tables --------
__global__ __launch_bounds__(256) void prep_all(
    const float* __restrict__ w0, const float* __restrict__ w1,
    const float* __restrict__ w2, const float* __restrict__ w3, u16* __restrict__ wTbase,
    const float* __restrict__ cw0, const float* __restrict__ g0, const float* __restrict__ bb0,
    const float* __restrict__ m0, const float* __restrict__ v0,
    const float* __restrict__ cw1, const float* __restrict__ g1, const float* __restrict__ bb1,
    const float* __restrict__ m1, const float* __restrict__ v1,
    const float* __restrict__ cw2, const float* __restrict__ g2, const float* __restrict__ bb2,
    const float* __restrict__ m2, const float* __restrict__ v2,
    float* __restrict__ cwfb, float* __restrict__ shb,
    const float* __restrict__ rpb_t, const float* __restrict__ tt,
    const float* __restrict__ tg, u16* __restrict__ btab,
    const float* __restrict__ rpb_m, u16* __restrict__ mtab) {
    __shared__ float t[32][33];
    const int id = blockIdx.x, tid = threadIdx.x;
    if (id < 1024) {
        const int z = id >> 8, rem = id & 255;
        const int bx = rem & 15, by = rem >> 4;
        const float* W = z == 0 ? w0 : z == 1 ? w1 : z == 2 ? w2 : w3;
        u16* WT = wTbase + (size_t)z * 262144;
        const int tx = tid & 31, ty = tid >> 5;
        for (int i = ty; i < 32; i += 8)
            t[i][tx] = W[(size_t)(by * 32 + i) * 512 + bx * 32 + tx];
        __syncthreads();
        for (int i = ty; i < 32; i += 8)
            WT[(size_t)(bx * 32 + i) * 512 + by * 32 + tx] = f2b(t[tx][i]);
    } else if (id < 1051) {
        const int rem = id - 1024;
        const int tap = rem % 9, br = rem / 9;
        const float* cw = br == 0 ? cw0 : br == 1 ? cw1 : cw2;
        const float* g  = br == 0 ? g0  : br == 1 ? g1  : g2;
        const float* bb = br == 0 ? bb0 : br == 1 ? bb1 : bb2;
        const float* m  = br == 0 ? m0  : br == 1 ? m1  : m2;
        const float* v  = br == 0 ? v0  : br == 1 ? v1  : v2;
        for (int c = tid; c < DM; c += 256) {
            const float inv = g[c] * rsqrtf(v[c] + 1e-5f);
            cwfb[(br * 9 + tap) * DM + c] = cw[c * 9 + tap] * inv;
            if (tap == 0) shb[br * DM + c] = bb[c] - m[c] * inv;
        }
    } else if (id < 4923) {
        const int rem = id - 1051;
        const int h = rem / NTGT, q = rem % NTGT;
        const int qh = q / 22, qw = q % 22;
        const float tgv = tg[h * NTGT + q];
        for (int k = tid; k < KPAD; k += 256) {
            float val;
            if (k < NTMP) val = (tt[h * NTMP + k] + tgv) * LOG2E;
            else if (k < NTOK) {
                const int kj = k - NTMP, kh = kj / 22, kw = kj % 22;
                val = rpb_t[((qh - kh + 21) * 43 + (qw - kw + 21)) * MH + h] * LOG2E;
            } else val = -1e30f;
            btab[((size_t)(h * NTGT + q)) * KPAD + k] = f2b(val);
        }
    } else {
        const int q = id - 4923, k = tid;
        const int qh = q >> 4, qw = q & 15, kh = k >> 4, kw = k & 15;
        mtab[q * 256 + k] = f2b(rpb_m[(qh - kh + 15) * 31 + (qw - kw + 15)] * LOG2E);
    }
}

// ---------------- fused depthwise 3x3 conv (+folded BN) for q,k,v ----------------
__global__ __launch_bounds__(256) void conv_bn3(
    const float* __restrict__ x,
    const float* __restrict__ cwfb, const float* __restrict__ shb,
    u16* __restrict__ o0, u16* __restrict__ o1, u16* __restrict__ o2) {
    const int bn = blockIdx.x * 2 + (threadIdx.x >> 7);
    const int c = (threadIdx.x & 127) * 4;
    const int b = bn / NTOK, n = bn % NTOK;
    const bool tmp = n < NTMP;
    const int L = tmp ? 16 : 22, base = tmp ? 0 : NTMP, p = n - base;
    const int ph = p / L, pw = p % L;
    float4 xv[9];
#pragma unroll
    for (int tap = 0; tap < 9; ++tap) {
        const int dh = tap / 3 - 1, dw = tap % 3 - 1;
        const int h2 = ph + dh, w2 = pw + dw;
        const bool ok = (h2 >= 0 && h2 < L && w2 >= 0 && w2 < L);
        xv[tap] = ok ? *(const float4*)(x + (size_t)(b * NTOK + base + h2 * L + w2) * DM + c)
                     : float4{0.f, 0.f, 0.f, 0.f};
    }
    const size_t o = (size_t)bn * DM + c;
    u16* out[3] = {o0, o1, o2};
#pragma unroll
    for (int br = 0; br < 3; ++br) {
        float4 acc = *(const float4*)(shb + br * DM + c);
#pragma unroll
        for (int tap = 0; tap < 9; ++tap) {
            const float4 wv = *(const float4*)(cwfb + (br * 9 + tap) * DM + c);
            acc.x = fmaf(wv.x, xv[tap].x, acc.x);
            acc.y = fmaf(wv.y, xv[tap].y, acc.y);
            acc.z = fmaf(wv.z, xv[tap].z, acc.z);
            acc.w = fmaf(wv.w, xv[tap].w, acc.w);
        }
        us4 r;
        r.x = f2b(acc.x); r.y = f2b(acc.y); r.z = f2b(acc.z); r.w = f2b(acc.w);
        *(us4*)(out[br] + o) = r;
    }
}

// ---- GEMM 64x128 tile, 4-buffer prefetch-3, counted vmcnt + raw s_barrier ----
#define STAGE(bf, kk) do {                                                           \
    gload16(asrc + (kk) * 32, &As[bf][w * 512]);                                     \
    gload16(bsrc0 + (kk) * 32, &Bs[bf][w * 1024]);                                   \
    gload16(bsrc1 + (kk) * 32, &Bs[bf][w * 1024 + 512]);                             \
} while (0)

#define GEMM_BODY(A, BT)                                                             \
    const int tid = threadIdx.x;                                                     \
    const int lane = tid & 63, w = tid >> 6;                                         \
    const int lr = lane & 15, lg = lane >> 4;                                        \
    const int wm = (w >> 1) * 32, wn = (w & 1) * 64;                                 \
    const int srow4 = lane >> 2;                                                     \
    const int sc = (lane & 3) ^ ((srow4 & 3) ^ ((srow4 >> 2) & 3));                  \
    const int flr = (lr & 3) ^ ((lr >> 2) & 3);                                      \
    const u16* asrc  = A  + (size_t)(gm0 + w * 16 + srow4) * 512 + sc * 8;           \
    const u16* bsrc0 = BT + (size_t)(gn0 + w * 32 + srow4) * 512 + sc * 8;           \
    const u16* bsrc1 = BT + (size_t)(gn0 + w * 32 + 16 + srow4) * 512 + sc * 8;      \
    f32x4 acc[2][4] = {};                                                            \
    STAGE(0, 0); STAGE(1, 1); STAGE(2, 2);                                           \
    _Pragma("unroll")                                                                \
    for (int kt = 0; kt < 16; ++kt) {                                                \
        const int cur = kt & 3;                                                      \
        if (kt < 13) {                                                               \
            STAGE((kt + 3) & 3, kt + 3);                                             \
            asm volatile("s_waitcnt vmcnt(9)" ::: "memory");                         \
        } else if (kt == 13) {                                                       \
            asm volatile("s_waitcnt vmcnt(6)" ::: "memory");                         \
        } else if (kt == 14) {                                                       \
            asm volatile("s_waitcnt vmcnt(3)" ::: "memory");                         \
        } else {                                                                     \
            asm volatile("s_waitcnt vmcnt(0)" ::: "memory");                         \
        }                                                                            \
        __builtin_amdgcn_s_barrier();                                                \
        asm volatile("" ::: "memory");                                               \
        short8 af[2], bfr[4];                                                        \
        _Pragma("unroll")                                                            \
        for (int i = 0; i < 2; ++i)                                                  \
            af[i] = *(const short8*)&As[cur][(wm + i * 16 + lr) * 32 + (lg ^ flr) * 8]; \
        _Pragma("unroll")                                                            \
        for (int j = 0; j < 4; ++j)                                                  \
            bfr[j] = *(const short8*)&Bs[cur][(wn + j * 16 + lr) * 32 + (lg ^ flr) * 8]; \
        _Pragma("unroll")                                                            \
        for (int i = 0; i < 2; ++i)                                                  \
            _Pragma("unroll")                                                        \
            for (int j = 0; j < 4; ++j)                                              \
                acc[i][j] = __builtin_amdgcn_mfma_f32_16x16x32_bf16(af[i], bfr[j], acc[i][j], 0, 0, 0); \
        asm volatile("" ::: "memory");                                               \
        __builtin_amdgcn_s_barrier();                                                \
    }

// Q/K/V GEMMs: z = blockIdx.z + zbase selects branch. z==2 writes vbT layout.
__global__ __launch_bounds__(256) void gemm_qkv(
    const u16* __restrict__ Aq, const u16* __restrict__ Ak, const u16* __restrict__ Av,
    const u16* __restrict__ wTb, const float* __restrict__ bq,
    const float* __restrict__ bk, const float* __restrict__ bv,
    u16* __restrict__ qout, u16* __restrict__ kout, u16* __restrict__ vbT, int zbase) {
    __shared__ u16 As[4][2048];
    __shared__ u16 Bs[4][4096];
    const int gm0 = blockIdx.x * 64, gn0 = blockIdx.y * 128;
    const int z = blockIdx.z + zbase;
    const u16* A = z == 0 ? Aq : z == 1 ? Ak : Av;
    const u16* BT = wTb + (size_t)z * 262144;
    const float* bias = z == 0 ? bq : z == 1 ? bk : bv;
    GEMM_BODY(A, BT)
    u16* lin = z == 0 ? qout : kout;
#pragma unroll
    for (int i = 0; i < 2; ++i)
#pragma unroll
        for (int j = 0; j < 4; ++j) {
            const int gc = gn0 + wn + j * 16 + lr;
            const float bvl = bias[gc];
#pragma unroll
            for (int r = 0; r < 4; ++r) {
                const int gr = gm0 + wm + i * 16 + lg * 4 + r;
                const float val = acc[i][j][r] + bvl;
                if (z == 2) {
                    const int b2 = gr / NTOK, k = gr - b2 * NTOK;
                    const int hh = gc >> 6, d = gc & 63;
                    vbT[((size_t)(b2 * MH + hh) * 64 + d) * KPAD + k] = f2b(val);
                } else {
                    lin[(size_t)gr * 512 + gc] = f2b(val);
                }
            }
        }
}

// final projection GEMM: f32 out
__global__ __launch_bounds__(256) void gemm_out(const u16* __restrict__ Ain,
                                                const u16* __restrict__ BTin,
                                                const float* __restrict__ bias,
                                                float* __restrict__ C) {
    __shared__ u16 As[4][2048];
    __shared__ u16 Bs[4][4096];
    const int gm0 = blockIdx.x * 64, gn0 = blockIdx.y * 128;
    GEMM_BODY(Ain, BTin)
#pragma unroll
    for (int i = 0; i < 2; ++i)
#pragma unroll
        for (int j = 0; j < 4; ++j) {
            const int gc = gn0 + wn + j * 16 + lr;
            const float bvl = bias[gc];
#pragma unroll
            for (int r = 0; r < 4; ++r) {
                const int gr = gm0 + wm + i * 16 + lg * 4 + r;
                C[(size_t)gr * 512 + gc] = acc[i][j][r] + bvl;
            }
        }
}

// ---------------- merged MFMA flash attention: 128 q-rows/block, O^T form ----------------
// 4 K/V LDS buffers, stage distance-2, bias register prefetch distance-1, ONE
// barrier per chunk. Issue order per iter kc: B(kc+1)[4], S(kc+2)[2]. FIFO:
// newer-than-B(kc) = S(kc+1)2 + B(kc+1)4 + S(kc+2)2 = 8 -> vmcnt(8) steady
// (6 at kc==NCH-2, 0 last). Prologue order S(0), B(0), S(1) makes iter-0 uniform.
// Buffer safety (single barrier, skew<1 iter): stager at kc+1 writes (kc+3)&3
// == (kc-1)&3, whose reads completed before barrier(kc+1) admission.
__global__ __launch_bounds__(256) void attn_all(const u16* __restrict__ qb,
                                                const u16* __restrict__ kb,
                                                const u16* __restrict__ vbT,
                                                const u16* __restrict__ btab,
                                                const u16* __restrict__ mtab,
                                                u16* __restrict__ attb) {
    __shared__ u16 Ks[4][32][64];       // keys x d  (8-chunk swizzle, 128B rows)
    __shared__ u16 VTs[4][64][32];      // d x keys  (4-chunk swizzle incl. >>2 term)
    __shared__ u16 Pb[2][4][16][32];    // per-(qtile,wave) P^T round-trip

    // XCD-bijective remap: 768 blocks % 8 == 0; 96/XCD = 16 (h,b) pairs x 6 tiles
    int wg = blockIdx.x + 6 * (blockIdx.y + 8 * blockIdx.z);
    wg = (wg & 7) * 96 + (wg >> 3);
    const int bx = wg % 6;
    const int hb = wg / 6;
    const int h = hb & 7, b = hb >> 3;

    const bool tgt = bx < 4;
    const int q0 = (tgt ? bx : bx - 4) * 128;
    const int NKr = tgt ? NTOK : NTMP;
    const int NCH = tgt ? 24 : 8;
    const int QTOT = tgt ? NTGT : NTMP;
    const int QOFF = tgt ? NTMP : 0;
    const int TK = tgt ? KPAD : 256;
    const int tid = threadIdx.x;
    const int w = tid >> 6, lane = tid & 63;
    const int lq = lane & 15, lg = lane >> 4;
    const int fq = (lq & 3) ^ ((lq >> 2) & 3);      // phase-safe 4-chunk swizzle
    const size_t brow = (size_t)b * NTOK;
    const float SCL = 0.125f * LOG2E;

    int qA = q0 + w * 16 + lq;       if (qA > QTOT - 1) qA = QTOT - 1;
    int qB = q0 + 64 + w * 16 + lq;  if (qB > QTOT - 1) qB = QTOT - 1;
    const u16* tbase = tgt ? (btab + (size_t)h * NTGT * KPAD) : mtab;
    const u16* trowA = tbase + (size_t)qA * TK;
    const u16* trowB = tbase + (size_t)qB * TK;

    short8 qfA[2], qfB[2];
#pragma unroll
    for (int dc = 0; dc < 2; ++dc) {
        qfA[dc] = *(const short8*)(qb + (brow + QOFF + qA) * DM + h * 64 + dc * 32 + lg * 8);
        qfB[dc] = *(const short8*)(qb + (brow + QOFF + qB) * DM + h * 64 + dc * 32 + lg * 8);
    }

    // staging: gload_lds, lane-linear LDS dest; source chunk pre-XORed with row fn
    const int krow = tid >> 3, ksc = tid & 7;
    const int vrow = tid >> 2, vsc = tid & 3;
    const int fv = (vrow & 3) ^ ((vrow >> 2) & 3);
    const size_t vbase = (size_t)(b * MH + h) * 64 * KPAD;
    const u16* kptr2 = kb + brow * DM + h * 64 + (ksc ^ (krow & 7)) * 8;
    const u16* vptr2 = vbT + vbase + (size_t)vrow * KPAD + (vsc ^ fv) * 8;
    const int NKm1 = NKr - 1;

    float mrunA = -1e30f, lrunA = 0.f, mrunB = -1e30f, lrunB = 0.f;
    f32x4 oTA[4] = {}, oTB[4] = {};

    // prologue: S(0), B(0), S(1)  (issue order matters for FIFO accounting)
    {
        const int keyc = krow < NKm1 ? krow : NKm1;
        gload16(kptr2 + (size_t)keyc * DM, &Ks[0][w * 8][0]);
        gload16(vptr2, &VTs[0][w * 16][0]);
    }
    us4 bcA0 = *(const us4*)(trowA + lg * 4);
    us4 bcA1 = *(const us4*)(trowA + 16 + lg * 4);
    us4 bcB0 = *(const us4*)(trowB + lg * 4);
    us4 bcB1 = *(const us4*)(trowB + 16 + lg * 4);
    {
        const int key = 32 + krow;
        const int keyc = key < NKm1 ? key : NKm1;
        gload16(kptr2 + (size_t)keyc * DM, &Ks[1][w * 8][0]);
        gload16(vptr2 + 32, &VTs[1][w * 16][0]);
    }

    for (int kc = 0; kc < NCH; ++kc) {
        const int cur = kc & 3;
        const bool more1 = (kc + 1 < NCH);   // bias prefetch
        const bool more2 = (kc + 2 < NCH);   // K/V stage prefetch
        us4 bnA0 = {0,0,0,0}, bnA1 = {0,0,0,0}, bnB0 = {0,0,0,0}, bnB1 = {0,0,0,0};
        if (more1) {
            bnA0 = *(const us4*)(trowA + (kc + 1) * 32 + lg * 4);
            bnA1 = *(const us4*)(trowA + (kc + 1) * 32 + 16 + lg * 4);
            bnB0 = *(const us4*)(trowB + (kc + 1) * 32 + lg * 4);
            bnB1 = *(const us4*)(trowB + (kc + 1) * 32 + 16 + lg * 4);
        }
        if (more2) {
            const int key = (kc + 2) * 32 + krow;
            const int keyc = key < NKm1 ? key : NKm1;
            gload16(kptr2 + (size_t)keyc * DM, &Ks[(kc + 2) & 3][w * 8][0]);
            gload16(vptr2 + (kc + 2) * 32, &VTs[(kc + 2) & 3][w * 16][0]);
        }
        if (more2) {
            asm volatile("s_waitcnt vmcnt(8)" ::: "memory");
        } else if (more1) {
            asm volatile("s_waitcnt vmcnt(6)" ::: "memory");
        } else {
            asm volatile("s_waitcnt vmcnt(0)" ::: "memory");
        }
        __builtin_amdgcn_s_barrier();
        asm volatile("" ::: "memory");

        // ---- S^T for both q-tiles: K-frags read once ----
        f32x4 sA0 = {}, sA1 = {}, sB0 = {}, sB1 = {};
        __builtin_amdgcn_s_setprio(1);
#pragma unroll
        for (int dc = 0; dc < 2; ++dc) {
            short8 a0 = *(const short8*)&Ks[cur][lq][((dc * 4 + lg) ^ (lq & 7)) * 8];
            short8 a1 = *(const short8*)&Ks[cur][16 + lq][((dc * 4 + lg) ^ (lq & 7)) * 8];
            sA0 = __builtin_amdgcn_mfma_f32_16x16x32_bf16(a0, qfA[dc], sA0, 0, 0, 0);
            sB0 = __builtin_amdgcn_mfma_f32_16x16x32_bf16(a0, qfB[dc], sB0, 0, 0, 0);
            sA1 = __builtin_amdgcn_mfma_f32_16x16x32_bf16(a1, qfA[dc], sA1, 0, 0, 0);
            sB1 = __builtin_amdgcn_mfma_f32_16x16x32_bf16(a1, qfB[dc], sB1, 0, 0, 0);
        }
        __builtin_amdgcn_s_setprio(0);

        // ---- softmax tile A ----
        {
            float sv[8];
            sv[0] = fmaf(sA0[0], SCL, b2f(bcA0.x)); sv[1] = fmaf(sA0[1], SCL, b2f(bcA0.y));
            sv[2] = fmaf(sA0[2], SCL, b2f(bcA0.z)); sv[3] = fmaf(sA0[3], SCL, b2f(bcA0.w));
            sv[4] = fmaf(sA1[0], SCL, b2f(bcA1.x)); sv[5] = fmaf(sA1[1], SCL, b2f(bcA1.y));
            sv[6] = fmaf(sA1[2], SCL, b2f(bcA1.z)); sv[7] = fmaf(sA1[3], SCL, b2f(bcA1.w));
            float cm = sv[0];
#pragma unroll
            for (int i = 1; i < 8; ++i) cm = fmaxf(cm, sv[i]);
            cm = fmaxf(cm, __shfl_xor(cm, 16));
            cm = fmaxf(cm, __shfl_xor(cm, 32));
            if (!__all(cm <= mrunA)) {
                const float mnew = fmaxf(mrunA, cm);
                const float alpha = fexp2(mrunA - mnew);
#pragma unroll
                for (int t = 0; t < 4; ++t)
#pragma unroll
                    for (int r = 0; r < 4; ++r) oTA[t][r] *= alpha;
                lrunA *= alpha;
                mrunA = mnew;
            }
            float pv[8], psum = 0.f;
#pragma unroll
            for (int i = 0; i < 8; ++i) { pv[i] = fexp2(sv[i] - mrunA); psum += pv[i]; }
            const int c0 = (((lg >> 1) ^ fq) & 3) * 8 + (lg & 1) * 4;
            const int c1 = (((2 + (lg >> 1)) ^ fq) & 3) * 8 + (lg & 1) * 4;
            *(uint2*)&Pb[0][w][lq][c0] = uint2{pk2(pv[0], pv[1]), pk2(pv[2], pv[3])};
            *(uint2*)&Pb[0][w][lq][c1] = uint2{pk2(pv[4], pv[5]), pk2(pv[6], pv[7])};
            psum += __shfl_xor(psum, 16);
            psum += __shfl_xor(psum, 32);
            lrunA += psum;
        }
        // ---- softmax tile B ----
        {
            float sv[8];
            sv[0] = fmaf(sB0[0], SCL, b2f(bcB0.x)); sv[1] = fmaf(sB0[1], SCL, b2f(bcB0.y));
            sv[2] = fmaf(sB0[2], SCL, b2f(bcB0.z)); sv[3] = fmaf(sB0[3], SCL, b2f(bcB0.w));
            sv[4] = fmaf(sB1[0], SCL, b2f(bcB1.x)); sv[5] = fmaf(sB1[1], SCL, b2f(bcB1.y));
            sv[6] = fmaf(sB1[2], SCL, b2f(bcB1.z)); sv[7] = fmaf(sB1[3], SCL, b2f(bcB1.w));
            float cm = sv[0];
#pragma unroll
            for (int i = 1; i < 8; ++i) cm = fmaxf(cm, sv[i]);
            cm = fmaxf(cm, __shfl_xor(cm, 16));
            cm = fmaxf(cm, __shfl_xor(cm, 32));
            if (!__all(cm <= mrunB)) {
                const float mnew = fmaxf(mrunB, cm);
                const float alpha = fexp2(mrunB - mnew);
#pragma unroll
                for (int t = 0; t < 4; ++t)
#pragma unroll
                    for (int r = 0; r < 4; ++r) oTB[t][r] *= alpha;
                lrunB *= alpha;
                mrunB = mnew;
            }
            float pv[8], psum = 0.f;
#pragma unroll
            for (int i = 0; i < 8; ++i) { pv[i] = fexp2(sv[i] - mrunB); psum += pv[i]; }
            const int c0 = (((lg >> 1) ^ fq) & 3) * 8 + (lg & 1) * 4;
            const int c1 = (((2 + (lg >> 1)) ^ fq) & 3) * 8 + (lg & 1) * 4;
            *(uint2*)&Pb[1][w][lq][c0] = uint2{pk2(pv[0], pv[1]), pk2(pv[2], pv[3])};
            *(uint2*)&Pb[1][w][lq][c1] = uint2{pk2(pv[4], pv[5]), pk2(pv[6], pv[7])};
            psum += __shfl_xor(psum, 16);
            psum += __shfl_xor(psum, 32);
            lrunB += psum;
        }

        asm volatile("s_waitcnt lgkmcnt(0)" ::: "memory");

        // ---- PV both tiles: V-frags read once ----
        short8 pfA = *(const short8*)&Pb[0][w][lq][((lg ^ fq) & 3) * 8];
        short8 pfB = *(const short8*)&Pb[1][w][lq][((lg ^ fq) & 3) * 8];
        __builtin_amdgcn_s_setprio(1);
#pragma unroll
        for (int t = 0; t < 4; ++t) {
            short8 vf = *(const short8*)&VTs[cur][t * 16 + lq][((lg ^ fq) & 3) * 8];
            oTA[t] = __builtin_amdgcn_mfma_f32_16x16x32_bf16(vf, pfA, oTA[t], 0, 0, 0);
            oTB[t] = __builtin_amdgcn_mfma_f32_16x16x32_bf16(vf, pfB, oTB[t], 0, 0, 0);
        }
        __builtin_amdgcn_s_setprio(0);

        bcA0 = bnA0; bcA1 = bnA1; bcB0 = bnB0; bcB1 = bnB1;
    }

    // epilogue: O[q][d] stores, q lane-local
    {
        const float linv = 1.f / lrunA;
        const int qrow = q0 + w * 16 + lq;
        if (qrow < QTOT) {
            u16* op = attb + (brow + QOFF + qrow) * DM + h * 64;
#pragma unroll
            for (int t = 0; t < 4; ++t)
                *(uint2*)(op + t * 16 + lg * 4) =
                    uint2{pk2(oTA[t][0] * linv, oTA[t][1] * linv),
                          pk2(oTA[t][2] * linv, oTA[t][3] * linv)};
        }
    }
    {
        const float linv = 1.f / lrunB;
        const int qrow = q0 + 64 + w * 16 + lq;
        if (qrow < QTOT) {
            u16* op = attb + (brow + QOFF + qrow) * DM + h * 64;
#pragma unroll
            for (int t = 0; t < 4; ++t)
                *(uint2*)(op + t * 16 + lg * 4) =
                    uint2{pk2(oTB[t][0] * linv, oTB[t][1] * linv),
                          pk2(oTB[t][2] * linv, oTB[t][3] * linv)};
        }
    }
}

// ---------------- launch ----------------
extern "C" void kernel_launch(void* const* d_in, const int* in_sizes, int n_in,
                              void* d_out, int out_size, void* d_ws, size_t ws_size,
                              hipStream_t stream) {
    const float* x = (const float*)d_in[0];
    const float* convw[3] = {(const float*)d_in[1], (const float*)d_in[6], (const float*)d_in[11]};
    const float* bng[3]   = {(const float*)d_in[2], (const float*)d_in[7], (const float*)d_in[12]};
    const float* bnb[3]   = {(const float*)d_in[3], (const float*)d_in[8], (const float*)d_in[13]};
    const float* bnm[3]   = {(const float*)d_in[4], (const float*)d_in[9], (const float*)d_in[14]};
    const float* bnv[3]   = {(const float*)d_in[5], (const float*)d_in[10], (const float*)d_in[15]};
    const float* w[4]     = {(const float*)d_in[16], (const float*)d_in[18], (const float*)d_in[20], (const float*)d_in[22]};
    const float* bias[4]  = {(const float*)d_in[17], (const float*)d_in[19], (const float*)d_in[21], (const float*)d_in[23]};
    const float* rpb_t = (const float*)d_in[24];
    const float* rpb_m = (const float*)d_in[25];
    const float* tt    = (const float*)d_in[26];
    const float* tg    = (const float*)d_in[27];

    char* p = (char*)d_ws;
    auto alloc = [&](size_t n) { char* r = p; p += (n + 255) & ~(size_t)255; return r; };
    const size_t SEQ = (size_t)MROWS * DM * 2;   // 12,124,160 B
    u16* wTb  = (u16*)alloc(4 * 524288);
    u16* cbq  = (u16*)alloc(SEQ);
    u16* cbk  = (u16*)alloc(SEQ);
    u16* cbv  = (u16*)alloc(SEQ);
    u16* kbuf = (u16*)alloc(SEQ);
    u16* vbT  = (u16*)alloc((size_t)16 * MH * 64 * KPAD * 2);   // 12,582,912
    u16* btab = (u16*)alloc((size_t)MH * NTGT * KPAD * 2);      // 5,947,392
    u16* mtab = (u16*)alloc(256 * 256 * 2);
    float* cwf = (float*)alloc(3 * 9 * DM * 4);
    float* shf = (float*)alloc(3 * DM * 4);
    const size_t used = (size_t)(p - (char*)d_ws);
    const bool merged = ws_size >= used + SEQ;
    u16* qbuf = merged ? (u16*)alloc(SEQ) : cbv;   // fallback aliases cbv
    u16* attb = cbq;   // cbq dead after Q-GEMM

    prep_all<<<5179, 256, 0, stream>>>(
        w[0], w[1], w[2], w[3], wTb,
        convw[0], bng[0], bnb[0], bnm[0], bnv[0],
        convw[1], bng[1], bnb[1], bnm[1], bnv[1],
        convw[2], bng[2], bnb[2], bnm[2], bnv[2], cwf, shf,
        rpb_t, tt, tg, btab, rpb_m, mtab);

    conv_bn3<<<MROWS / 2, 256, 0, stream>>>(x, cwf, shf, cbq, cbk, cbv);

    if (merged) {
        gemm_qkv<<<dim3(185, 4, 3), 256, 0, stream>>>(cbq, cbk, cbv, wTb,
                                                      bias[0], bias[1], bias[2],
                                                      qbuf, kbuf, vbT, 0);
    } else {
        // V first (reads cbv), then Q+K (Q writes qbuf==cbv) — stream order keeps it safe
        gemm_qkv<<<dim3(185, 4, 1), 256, 0, stream>>>(cbq, cbk, cbv, wTb,
                                                      bias[0], bias[1], bias[2],
                                                      qbuf, kbuf, vbT, 2);
        gemm_qkv<<<dim3(185, 4, 2), 256, 0, stream>>>(cbq, cbk, cbv, wTb,
                                                      bias[0], bias[1], bias[2],
                                                      qbuf, kbuf, vbT, 0);
    }

    attn_all<<<dim3(6, 8, 16), 256, 0, stream>>>(qbuf, kbuf, vbT, btab, mtab, attb);

    gemm_out<<<dim3(185, 4), 256, 0, stream>>>(attb, wTb + 3 * 262144, bias[3], (float*)d_out);
}

// Round 27
// 166.149 us; speedup vs baseline: 1.1436x; 1.1436x over previous
//
#include <hip/hip_runtime.h>
#include <hip/hip_bf16.h>

typedef unsigned short u16;
typedef unsigned int u32;
typedef __attribute__((ext_vector_type(8))) short short8;   // 8 bf16 (4 VGPRs)
typedef __attribute__((ext_vector_type(4))) float f32x4;

#define NTOK 740
#define NTMP 256
#define NTGT 484
#define DM   512
#define MH   8
#define MROWS 11840   // B*NTOK = 16*740
#define KPAD 768
#define LOG2E 1.4426950408889634f

__device__ __forceinline__ float b2f(u16 u) {
    union { unsigned int i; float f; } x; x.i = ((unsigned int)u) << 16; return x.f;
}
__device__ __forceinline__ u16 f2b(float f) {
    union { float f; unsigned int i; } x; x.f = f;
    unsigned int r = x.i + 0x7FFFu + ((x.i >> 16) & 1u);   // RNE
    return (u16)(r >> 16);
}
__device__ __forceinline__ u32 pk2(float a, float b) {
    union { __hip_bfloat162 h; u32 u; } p;
    p.h = __float22bfloat162_rn(float2{a, b});
    return p.u;
}
__device__ __forceinline__ float fexp2(float x) {   // raw v_exp_f32 (log2 domain)
    return __builtin_amdgcn_exp2f(x);
}
struct alignas(8) us4 { u16 x, y, z, w; };

__device__ __forceinline__ void gload16(const void* g, void* l) {
    __builtin_amdgcn_global_load_lds(
        (const __attribute__((address_space(1))) void*)g,
        (__attribute__((address_space(3))) void*)l, 16, 0, 0);
}

// -------- merged prologue: weight transposes + conv-weight fold + bias tables --------
__global__ __launch_bounds__(256) void prep_all(
    const float* __restrict__ w0, const float* __restrict__ w1,
    const float* __restrict__ w2, const float* __restrict__ w3, u16* __restrict__ wTbase,
    const float* __restrict__ cw0, const float* __restrict__ g0, const float* __restrict__ bb0,
    const float* __restrict__ m0, const float* __restrict__ v0,
    const float* __restrict__ cw1, const float* __restrict__ g1, const float* __restrict__ bb1,
    const float* __restrict__ m1, const float* __restrict__ v1,
    const float* __restrict__ cw2, const float* __restrict__ g2, const float* __restrict__ bb2,
    const float* __restrict__ m2, const float* __restrict__ v2,
    float* __restrict__ cwfb, float* __restrict__ shb,
    const float* __restrict__ rpb_t, const float* __restrict__ tt,
    const float* __restrict__ tg, u16* __restrict__ btab,
    const float* __restrict__ rpb_m, u16* __restrict__ mtab) {
    __shared__ float t[32][33];
    const int id = blockIdx.x, tid = threadIdx.x;
    if (id < 1024) {
        const int z = id >> 8, rem = id & 255;
        const int bx = rem & 15, by = rem >> 4;
        const float* W = z == 0 ? w0 : z == 1 ? w1 : z == 2 ? w2 : w3;
        u16* WT = wTbase + (size_t)z * 262144;
        const int tx = tid & 31, ty = tid >> 5;
        for (int i = ty; i < 32; i += 8)
            t[i][tx] = W[(size_t)(by * 32 + i) * 512 + bx * 32 + tx];
        __syncthreads();
        for (int i = ty; i < 32; i += 8)
            WT[(size_t)(bx * 32 + i) * 512 + by * 32 + tx] = f2b(t[tx][i]);
    } else if (id < 1051) {
        const int rem = id - 1024;
        const int tap = rem % 9, br = rem / 9;
        const float* cw = br == 0 ? cw0 : br == 1 ? cw1 : cw2;
        const float* g  = br == 0 ? g0  : br == 1 ? g1  : g2;
        const float* bb = br == 0 ? bb0 : br == 1 ? bb1 : bb2;
        const float* m  = br == 0 ? m0  : br == 1 ? m1  : m2;
        const float* v  = br == 0 ? v0  : br == 1 ? v1  : v2;
        for (int c = tid; c < DM; c += 256) {
            const float inv = g[c] * rsqrtf(v[c] + 1e-5f);
            cwfb[(br * 9 + tap) * DM + c] = cw[c * 9 + tap] * inv;
            if (tap == 0) shb[br * DM + c] = bb[c] - m[c] * inv;
        }
    } else if (id < 4923) {
        const int rem = id - 1051;
        const int h = rem / NTGT, q = rem % NTGT;
        const int qh = q / 22, qw = q % 22;
        const float tgv = tg[h * NTGT + q];
        for (int k = tid; k < KPAD; k += 256) {
            float val;
            if (k < NTMP) val = (tt[h * NTMP + k] + tgv) * LOG2E;
            else if (k < NTOK) {
                const int kj = k - NTMP, kh = kj / 22, kw = kj % 22;
                val = rpb_t[((qh - kh + 21) * 43 + (qw - kw + 21)) * MH + h] * LOG2E;
            } else val = -1e30f;
            btab[((size_t)(h * NTGT + q)) * KPAD + k] = f2b(val);
        }
    } else {
        const int q = id - 4923, k = tid;
        const int qh = q >> 4, qw = q & 15, kh = k >> 4, kw = k & 15;
        mtab[q * 256 + k] = f2b(rpb_m[(qh - kh + 15) * 31 + (qw - kw + 15)] * LOG2E);
    }
}

// ---------------- fused depthwise 3x3 conv (+folded BN) for q,k,v ----------------
__global__ __launch_bounds__(256) void conv_bn3(
    const float* __restrict__ x,
    const float* __restrict__ cwfb, const float* __restrict__ shb,
    u16* __restrict__ o0, u16* __restrict__ o1, u16* __restrict__ o2) {
    const int bn = blockIdx.x * 2 + (threadIdx.x >> 7);
    const int c = (threadIdx.x & 127) * 4;
    const int b = bn / NTOK, n = bn % NTOK;
    const bool tmp = n < NTMP;
    const int L = tmp ? 16 : 22, base = tmp ? 0 : NTMP, p = n - base;
    const int ph = p / L, pw = p % L;
    float4 xv[9];
#pragma unroll
    for (int tap = 0; tap < 9; ++tap) {
        const int dh = tap / 3 - 1, dw = tap % 3 - 1;
        const int h2 = ph + dh, w2 = pw + dw;
        const bool ok = (h2 >= 0 && h2 < L && w2 >= 0 && w2 < L);
        xv[tap] = ok ? *(const float4*)(x + (size_t)(b * NTOK + base + h2 * L + w2) * DM + c)
                     : float4{0.f, 0.f, 0.f, 0.f};
    }
    const size_t o = (size_t)bn * DM + c;
    u16* out[3] = {o0, o1, o2};
#pragma unroll
    for (int br = 0; br < 3; ++br) {
        float4 acc = *(const float4*)(shb + br * DM + c);
#pragma unroll
        for (int tap = 0; tap < 9; ++tap) {
            const float4 wv = *(const float4*)(cwfb + (br * 9 + tap) * DM + c);
            acc.x = fmaf(wv.x, xv[tap].x, acc.x);
            acc.y = fmaf(wv.y, xv[tap].y, acc.y);
            acc.z = fmaf(wv.z, xv[tap].z, acc.z);
            acc.w = fmaf(wv.w, xv[tap].w, acc.w);
        }
        us4 r;
        r.x = f2b(acc.x); r.y = f2b(acc.y); r.z = f2b(acc.z); r.w = f2b(acc.w);
        *(us4*)(out[br] + o) = r;
    }
}

// ---- GEMM 64x128 tile, 4-buffer prefetch-3, counted vmcnt + raw s_barrier ----
#define STAGE(bf, kk) do {                                                           \
    gload16(asrc + (kk) * 32, &As[bf][w * 512]);                                     \
    gload16(bsrc0 + (kk) * 32, &Bs[bf][w * 1024]);                                   \
    gload16(bsrc1 + (kk) * 32, &Bs[bf][w * 1024 + 512]);                             \
} while (0)

#define GEMM_BODY(A, BT)                                                             \
    const int tid = threadIdx.x;                                                     \
    const int lane = tid & 63, w = tid >> 6;                                         \
    const int lr = lane & 15, lg = lane >> 4;                                        \
    const int wm = (w >> 1) * 32, wn = (w & 1) * 64;                                 \
    const int srow4 = lane >> 2;                                                     \
    const int sc = (lane & 3) ^ ((srow4 & 3) ^ ((srow4 >> 2) & 3));                  \
    const int flr = (lr & 3) ^ ((lr >> 2) & 3);                                      \
    const u16* asrc  = A  + (size_t)(gm0 + w * 16 + srow4) * 512 + sc * 8;           \
    const u16* bsrc0 = BT + (size_t)(gn0 + w * 32 + srow4) * 512 + sc * 8;           \
    const u16* bsrc1 = BT + (size_t)(gn0 + w * 32 + 16 + srow4) * 512 + sc * 8;      \
    f32x4 acc[2][4] = {};                                                            \
    STAGE(0, 0); STAGE(1, 1); STAGE(2, 2);                                           \
    _Pragma("unroll")                                                                \
    for (int kt = 0; kt < 16; ++kt) {                                                \
        const int cur = kt & 3;                                                      \
        if (kt < 13) {                                                               \
            STAGE((kt + 3) & 3, kt + 3);                                             \
            asm volatile("s_waitcnt vmcnt(9)" ::: "memory");                         \
        } else if (kt == 13) {                                                       \
            asm volatile("s_waitcnt vmcnt(6)" ::: "memory");                         \
        } else if (kt == 14) {                                                       \
            asm volatile("s_waitcnt vmcnt(3)" ::: "memory");                         \
        } else {                                                                     \
            asm volatile("s_waitcnt vmcnt(0)" ::: "memory");                         \
        }                                                                            \
        __builtin_amdgcn_s_barrier();                                                \
        asm volatile("" ::: "memory");                                               \
        short8 af[2], bfr[4];                                                        \
        _Pragma("unroll")                                                            \
        for (int i = 0; i < 2; ++i)                                                  \
            af[i] = *(const short8*)&As[cur][(wm + i * 16 + lr) * 32 + (lg ^ flr) * 8]; \
        _Pragma("unroll")                                                            \
        for (int j = 0; j < 4; ++j)                                                  \
            bfr[j] = *(const short8*)&Bs[cur][(wn + j * 16 + lr) * 32 + (lg ^ flr) * 8]; \
        _Pragma("unroll")                                                            \
        for (int i = 0; i < 2; ++i)                                                  \
            _Pragma("unroll")                                                        \
            for (int j = 0; j < 4; ++j)                                              \
                acc[i][j] = __builtin_amdgcn_mfma_f32_16x16x32_bf16(af[i], bfr[j], acc[i][j], 0, 0, 0); \
        asm volatile("" ::: "memory");                                               \
        __builtin_amdgcn_s_barrier();                                                \
    }

// Q/K/V GEMMs: z = blockIdx.z + zbase selects branch. z==2 writes vbT layout.
__global__ __launch_bounds__(256) void gemm_qkv(
    const u16* __restrict__ Aq, const u16* __restrict__ Ak, const u16* __restrict__ Av,
    const u16* __restrict__ wTb, const float* __restrict__ bq,
    const float* __restrict__ bk, const float* __restrict__ bv,
    u16* __restrict__ qout, u16* __restrict__ kout, u16* __restrict__ vbT, int zbase) {
    __shared__ u16 As[4][2048];
    __shared__ u16 Bs[4][4096];
    const int gm0 = blockIdx.x * 64, gn0 = blockIdx.y * 128;
    const int z = blockIdx.z + zbase;
    const u16* A = z == 0 ? Aq : z == 1 ? Ak : Av;
    const u16* BT = wTb + (size_t)z * 262144;
    const float* bias = z == 0 ? bq : z == 1 ? bk : bv;
    GEMM_BODY(A, BT)
    u16* lin = z == 0 ? qout : kout;
#pragma unroll
    for (int i = 0; i < 2; ++i)
#pragma unroll
        for (int j = 0; j < 4; ++j) {
            const int gc = gn0 + wn + j * 16 + lr;
            const float bvl = bias[gc];
#pragma unroll
            for (int r = 0; r < 4; ++r) {
                const int gr = gm0 + wm + i * 16 + lg * 4 + r;
                const float val = acc[i][j][r] + bvl;
                if (z == 2) {
                    const int b2 = gr / NTOK, k = gr - b2 * NTOK;
                    const int hh = gc >> 6, d = gc & 63;
                    vbT[((size_t)(b2 * MH + hh) * 64 + d) * KPAD + k] = f2b(val);
                } else {
                    lin[(size_t)gr * 512 + gc] = f2b(val);
                }
            }
        }
}

// final projection GEMM: f32 out
__global__ __launch_bounds__(256) void gemm_out(const u16* __restrict__ Ain,
                                                const u16* __restrict__ BTin,
                                                const float* __restrict__ bias,
                                                float* __restrict__ C) {
    __shared__ u16 As[4][2048];
    __shared__ u16 Bs[4][4096];
    const int gm0 = blockIdx.x * 64, gn0 = blockIdx.y * 128;
    GEMM_BODY(Ain, BTin)
#pragma unroll
    for (int i = 0; i < 2; ++i)
#pragma unroll
        for (int j = 0; j < 4; ++j) {
            const int gc = gn0 + wn + j * 16 + lr;
            const float bvl = bias[gc];
#pragma unroll
            for (int r = 0; r < 4; ++r) {
                const int gr = gm0 + wm + i * 16 + lg * 4 + r;
                C[(size_t)gr * 512 + gc] = acc[i][j][r] + bvl;
            }
        }
}

// ---------------- merged MFMA flash attention: 128 q-rows/block, O^T form ----------------
// 3 LDS buffers + prefetch-distance-1 -> ONE barrier per chunk. (32 KB is the attn
// LDS ceiling: 40 KB (R26) and 48 KB (R18) both cut residency below the 3-blocks/CU
// grid supply and regressed.)
__global__ __launch_bounds__(256) void attn_all(const u16* __restrict__ qb,
                                                const u16* __restrict__ kb,
                                                const u16* __restrict__ vbT,
                                                const u16* __restrict__ btab,
                                                const u16* __restrict__ mtab,
                                                u16* __restrict__ attb) {
    __shared__ u16 Ks[3][32][64];       // keys x d  (8-chunk swizzle, 128B rows)
    __shared__ u16 VTs[3][64][32];      // d x keys  (4-chunk swizzle incl. >>2 term)
    __shared__ u16 Pb[2][4][16][32];    // per-(qtile,wave) P^T round-trip

    // XCD-bijective remap: 768 blocks % 8 == 0; 96/XCD = 16 (h,b) pairs x 6 tiles
    int wg = blockIdx.x + 6 * (blockIdx.y + 8 * blockIdx.z);
    wg = (wg & 7) * 96 + (wg >> 3);
    const int bx = wg % 6;
    const int hb = wg / 6;
    const int h = hb & 7, b = hb >> 3;

    const bool tgt = bx < 4;
    const int q0 = (tgt ? bx : bx - 4) * 128;
    const int NKr = tgt ? NTOK : NTMP;
    const int NCH = tgt ? 24 : 8;
    const int QTOT = tgt ? NTGT : NTMP;
    const int QOFF = tgt ? NTMP : 0;
    const int TK = tgt ? KPAD : 256;
    const int tid = threadIdx.x;
    const int w = tid >> 6, lane = tid & 63;
    const int lq = lane & 15, lg = lane >> 4;
    const int fq = (lq & 3) ^ ((lq >> 2) & 3);      // phase-safe 4-chunk swizzle
    const size_t brow = (size_t)b * NTOK;
    const float SCL = 0.125f * LOG2E;

    int qA = q0 + w * 16 + lq;       if (qA > QTOT - 1) qA = QTOT - 1;
    int qB = q0 + 64 + w * 16 + lq;  if (qB > QTOT - 1) qB = QTOT - 1;
    const u16* tbase = tgt ? (btab + (size_t)h * NTGT * KPAD) : mtab;
    const u16* trowA = tbase + (size_t)qA * TK;
    const u16* trowB = tbase + (size_t)qB * TK;

    short8 qfA[2], qfB[2];
#pragma unroll
    for (int dc = 0; dc < 2; ++dc) {
        qfA[dc] = *(const short8*)(qb + (brow + QOFF + qA) * DM + h * 64 + dc * 32 + lg * 8);
        qfB[dc] = *(const short8*)(qb + (brow + QOFF + qB) * DM + h * 64 + dc * 32 + lg * 8);
    }

    // staging: gload_lds, lane-linear LDS dest; source chunk pre-XORed with row fn
    const int krow = tid >> 3, ksc = tid & 7;
    const int vrow = tid >> 2, vsc = tid & 3;
    const int fv = (vrow & 3) ^ ((vrow >> 2) & 3);
    const size_t vbase = (size_t)(b * MH + h) * 64 * KPAD;
    const u16* kptr2 = kb + brow * DM + h * 64 + (ksc ^ (krow & 7)) * 8;
    const u16* vptr2 = vbT + vbase + (size_t)vrow * KPAD + (vsc ^ fv) * 8;
    const int NKm1 = NKr - 1;

    float mrunA = -1e30f, lrunA = 0.f, mrunB = -1e30f, lrunB = 0.f;
    f32x4 oTA[4] = {}, oTB[4] = {};

    {   // prologue: stage chunk 0 (async; 2 VMEM ops)
        const int keyc = krow < NKm1 ? krow : NKm1;
        gload16(kptr2 + (size_t)keyc * DM, &Ks[0][w * 8][0]);
        gload16(vptr2, &VTs[0][w * 16][0]);
    }

    int cur = 0;
    for (int kc = 0; kc < NCH; ++kc) {
        const int nxt = cur + 1 < 3 ? cur + 1 : 0;
        const bool more = (kc + 1 < NCH);
        // ---- bias loads for THIS chunk (issued before next-chunk staging) ----
        us4 bcA0 = *(const us4*)(trowA + kc * 32 + lg * 4);
        us4 bcA1 = *(const us4*)(trowA + kc * 32 + 16 + lg * 4);
        us4 bcB0 = *(const us4*)(trowB + kc * 32 + lg * 4);
        us4 bcB1 = *(const us4*)(trowB + kc * 32 + 16 + lg * 4);
        if (more) {
            const int key = (kc + 1) * 32 + krow;
            const int keyc = key < NKm1 ? key : NKm1;
            gload16(kptr2 + (size_t)keyc * DM, &Ks[nxt][w * 8][0]);
            gload16(vptr2 + (kc + 1) * 32, &VTs[nxt][w * 16][0]);
            asm volatile("s_waitcnt vmcnt(2)" ::: "memory");   // this chunk's K/V + bias done
        } else {
            asm volatile("s_waitcnt vmcnt(0)" ::: "memory");
        }
        __builtin_amdgcn_s_barrier();
        asm volatile("" ::: "memory");

        // ---- S^T for both q-tiles: K-frags read once ----
        f32x4 sA0 = {}, sA1 = {}, sB0 = {}, sB1 = {};
        __builtin_amdgcn_s_setprio(1);
#pragma unroll
        for (int dc = 0; dc < 2; ++dc) {
            short8 a0 = *(const short8*)&Ks[cur][lq][((dc * 4 + lg) ^ (lq & 7)) * 8];
            short8 a1 = *(const short8*)&Ks[cur][16 + lq][((dc * 4 + lg) ^ (lq & 7)) * 8];
            sA0 = __builtin_amdgcn_mfma_f32_16x16x32_bf16(a0, qfA[dc], sA0, 0, 0, 0);
            sB0 = __builtin_amdgcn_mfma_f32_16x16x32_bf16(a0, qfB[dc], sB0, 0, 0, 0);
            sA1 = __builtin_amdgcn_mfma_f32_16x16x32_bf16(a1, qfA[dc], sA1, 0, 0, 0);
            sB1 = __builtin_amdgcn_mfma_f32_16x16x32_bf16(a1, qfB[dc], sB1, 0, 0, 0);
        }
        __builtin_amdgcn_s_setprio(0);

        // ---- softmax tile A ----
        {
            float sv[8];
            sv[0] = fmaf(sA0[0], SCL, b2f(bcA0.x)); sv[1] = fmaf(sA0[1], SCL, b2f(bcA0.y));
            sv[2] = fmaf(sA0[2], SCL, b2f(bcA0.z)); sv[3] = fmaf(sA0[3], SCL, b2f(bcA0.w));
            sv[4] = fmaf(sA1[0], SCL, b2f(bcA1.x)); sv[5] = fmaf(sA1[1], SCL, b2f(bcA1.y));
            sv[6] = fmaf(sA1[2], SCL, b2f(bcA1.z)); sv[7] = fmaf(sA1[3], SCL, b2f(bcA1.w));
            float cm = sv[0];
#pragma unroll
            for (int i = 1; i < 8; ++i) cm = fmaxf(cm, sv[i]);
            cm = fmaxf(cm, __shfl_xor(cm, 16));
            cm = fmaxf(cm, __shfl_xor(cm, 32));
            if (!__all(cm <= mrunA)) {
                const float mnew = fmaxf(mrunA, cm);
                const float alpha = fexp2(mrunA - mnew);
#pragma unroll
                for (int t = 0; t < 4; ++t)
#pragma unroll
                    for (int r = 0; r < 4; ++r) oTA[t][r] *= alpha;
                lrunA *= alpha;
                mrunA = mnew;
            }
            float pv[8], psum = 0.f;
#pragma unroll
            for (int i = 0; i < 8; ++i) { pv[i] = fexp2(sv[i] - mrunA); psum += pv[i]; }
            const int c0 = (((lg >> 1) ^ fq) & 3) * 8 + (lg & 1) * 4;
            const int c1 = (((2 + (lg >> 1)) ^ fq) & 3) * 8 + (lg & 1) * 4;
            *(uint2*)&Pb[0][w][lq][c0] = uint2{pk2(pv[0], pv[1]), pk2(pv[2], pv[3])};
            *(uint2*)&Pb[0][w][lq][c1] = uint2{pk2(pv[4], pv[5]), pk2(pv[6], pv[7])};
            psum += __shfl_xor(psum, 16);
            psum += __shfl_xor(psum, 32);
            lrunA += psum;
        }
        // ---- softmax tile B ----
        {
            float sv[8];
            sv[0] = fmaf(sB0[0], SCL, b2f(bcB0.x)); sv[1] = fmaf(sB0[1], SCL, b2f(bcB0.y));
            sv[2] = fmaf(sB0[2], SCL, b2f(bcB0.z)); sv[3] = fmaf(sB0[3], SCL, b2f(bcB0.w));
            sv[4] = fmaf(sB1[0], SCL, b2f(bcB1.x)); sv[5] = fmaf(sB1[1], SCL, b2f(bcB1.y));
            sv[6] = fmaf(sB1[2], SCL, b2f(bcB1.z)); sv[7] = fmaf(sB1[3], SCL, b2f(bcB1.w));
            float cm = sv[0];
#pragma unroll
            for (int i = 1; i < 8; ++i) cm = fmaxf(cm, sv[i]);
            cm = fmaxf(cm, __shfl_xor(cm, 16));
            cm = fmaxf(cm, __shfl_xor(cm, 32));
            if (!__all(cm <= mrunB)) {
                const float mnew = fmaxf(mrunB, cm);
                const float alpha = fexp2(mrunB - mnew);
#pragma unroll
                for (int t = 0; t < 4; ++t)
#pragma unroll
                    for (int r = 0; r < 4; ++r) oTB[t][r] *= alpha;
                lrunB *= alpha;
                mrunB = mnew;
            }
            float pv[8], psum = 0.f;
#pragma unroll
            for (int i = 0; i < 8; ++i) { pv[i] = fexp2(sv[i] - mrunB); psum += pv[i]; }
            const int c0 = (((lg >> 1) ^ fq) & 3) * 8 + (lg & 1) * 4;
            const int c1 = (((2 + (lg >> 1)) ^ fq) & 3) * 8 + (lg & 1) * 4;
            *(uint2*)&Pb[1][w][lq][c0] = uint2{pk2(pv[0], pv[1]), pk2(pv[2], pv[3])};
            *(uint2*)&Pb[1][w][lq][c1] = uint2{pk2(pv[4], pv[5]), pk2(pv[6], pv[7])};
            psum += __shfl_xor(psum, 16);
            psum += __shfl_xor(psum, 32);
            lrunB += psum;
        }

        asm volatile("s_waitcnt lgkmcnt(0)" ::: "memory");

        // ---- PV both tiles: V-frags read once ----
        short8 pfA = *(const short8*)&Pb[0][w][lq][((lg ^ fq) & 3) * 8];
        short8 pfB = *(const short8*)&Pb[1][w][lq][((lg ^ fq) & 3) * 8];
        __builtin_amdgcn_s_setprio(1);
#pragma unroll
        for (int t = 0; t < 4; ++t) {
            short8 vf = *(const short8*)&VTs[cur][t * 16 + lq][((lg ^ fq) & 3) * 8];
            oTA[t] = __builtin_amdgcn_mfma_f32_16x16x32_bf16(vf, pfA, oTA[t], 0, 0, 0);
            oTB[t] = __builtin_amdgcn_mfma_f32_16x16x32_bf16(vf, pfB, oTB[t], 0, 0, 0);
        }
        __builtin_amdgcn_s_setprio(0);
        cur = nxt;
    }

    // epilogue: O[q][d] stores, q lane-local
    {
        const float linv = 1.f / lrunA;
        const int qrow = q0 + w * 16 + lq;
        if (qrow < QTOT) {
            u16* op = attb + (brow + QOFF + qrow) * DM + h * 64;
#pragma unroll
            for (int t = 0; t < 4; ++t)
                *(uint2*)(op + t * 16 + lg * 4) =
                    uint2{pk2(oTA[t][0] * linv, oTA[t][1] * linv),
                          pk2(oTA[t][2] * linv, oTA[t][3] * linv)};
        }
    }
    {
        const float linv = 1.f / lrunB;
        const int qrow = q0 + 64 + w * 16 + lq;
        if (qrow < QTOT) {
            u16* op = attb + (brow + QOFF + qrow) * DM + h * 64;
#pragma unroll
            for (int t = 0; t < 4; ++t)
                *(uint2*)(op + t * 16 + lg * 4) =
                    uint2{pk2(oTB[t][0] * linv, oTB[t][1] * linv),
                          pk2(oTB[t][2] * linv, oTB[t][3] * linv)};
        }
    }
}

// ---------------- launch ----------------
extern "C" void kernel_launch(void* const* d_in, const int* in_sizes, int n_in,
                              void* d_out, int out_size, void* d_ws, size_t ws_size,
                              hipStream_t stream) {
    const float* x = (const float*)d_in[0];
    const float* convw[3] = {(const float*)d_in[1], (const float*)d_in[6], (const float*)d_in[11]};
    const float* bng[3]   = {(const float*)d_in[2], (const float*)d_in[7], (const float*)d_in[12]};
    const float* bnb[3]   = {(const float*)d_in[3], (const float*)d_in[8], (const float*)d_in[13]};
    const float* bnm[3]   = {(const float*)d_in[4], (const float*)d_in[9], (const float*)d_in[14]};
    const float* bnv[3]   = {(const float*)d_in[5], (const float*)d_in[10], (const float*)d_in[15]};
    const float* w[4]     = {(const float*)d_in[16], (const float*)d_in[18], (const float*)d_in[20], (const float*)d_in[22]};
    const float* bias[4]  = {(const float*)d_in[17], (const float*)d_in[19], (const float*)d_in[21], (const float*)d_in[23]};
    const float* rpb_t = (const float*)d_in[24];
    const float* rpb_m = (const float*)d_in[25];
    const float* tt    = (const float*)d_in[26];
    const float* tg    = (const float*)d_in[27];

    char* p = (char*)d_ws;
    auto alloc = [&](size_t n) { char* r = p; p += (n + 255) & ~(size_t)255; return r; };
    const size_t SEQ = (size_t)MROWS * DM * 2;   // 12,124,160 B
    u16* wTb  = (u16*)alloc(4 * 524288);
    u16* cbq  = (u16*)alloc(SEQ);
    u16* cbk  = (u16*)alloc(SEQ);
    u16* cbv  = (u16*)alloc(SEQ);
    u16* kbuf = (u16*)alloc(SEQ);
    u16* vbT  = (u16*)alloc((size_t)16 * MH * 64 * KPAD * 2);   // 12,582,912
    u16* btab = (u16*)alloc((size_t)MH * NTGT * KPAD * 2);      // 5,947,392
    u16* mtab = (u16*)alloc(256 * 256 * 2);
    float* cwf = (float*)alloc(3 * 9 * DM * 4);
    float* shf = (float*)alloc(3 * DM * 4);
    const size_t used = (size_t)(p - (char*)d_ws);
    const bool merged = ws_size >= used + SEQ;
    u16* qbuf = merged ? (u16*)alloc(SEQ) : cbv;   // fallback aliases cbv
    u16* attb = cbq;   // cbq dead after Q-GEMM

    prep_all<<<5179, 256, 0, stream>>>(
        w[0], w[1], w[2], w[3], wTb,
        convw[0], bng[0], bnb[0], bnm[0], bnv[0],
        convw[1], bng[1], bnb[1], bnm[1], bnv[1],
        convw[2], bng[2], bnb[2], bnm[2], bnv[2], cwf, shf,
        rpb_t, tt, tg, btab, rpb_m, mtab);

    conv_bn3<<<MROWS / 2, 256, 0, stream>>>(x, cwf, shf, cbq, cbk, cbv);

    if (merged) {
        gemm_qkv<<<dim3(185, 4, 3), 256, 0, stream>>>(cbq, cbk, cbv, wTb,
                                                      bias[0], bias[1], bias[2],
                                                      qbuf, kbuf, vbT, 0);
    } else {
        // V first (reads cbv), then Q+K (Q writes qbuf==cbv) — stream order keeps it safe
        gemm_qkv<<<dim3(185, 4, 1), 256, 0, stream>>>(cbq, cbk, cbv, wTb,
                                                      bias[0], bias[1], bias[2],
                                                      qbuf, kbuf, vbT, 2);
        gemm_qkv<<<dim3(185, 4, 2), 256, 0, stream>>>(cbq, cbk, cbv, wTb,
                                                      bias[0], bias[1], bias[2],
                                                      qbuf, kbuf, vbT, 0);
    }

    attn_all<<<dim3(6, 8, 16), 256, 0, stream>>>(qbuf, kbuf, vbT, btab, mtab, attb);

    gemm_out<<<dim3(185, 4), 256, 0, stream>>>(attb, wTb + 3 * 262144, bias[3], (float*)d_out);
}

// Round 28
// 164.925 us; speedup vs baseline: 1.1521x; 1.0074x over previous
//
#include <hip/hip_runtime.h>
#include <hip/hip_bf16.h>

typedef unsigned short u16;
typedef unsigned int u32;
typedef __attribute__((ext_vector_type(8))) short short8;   // 8 bf16 (4 VGPRs)
typedef __attribute__((ext_vector_type(4))) float f32x4;

#define NTOK 740
#define NTMP 256
#define NTGT 484
#define DM   512
#define MH   8
#define MROWS 11840   // B*NTOK = 16*740
#define KPAD 768
#define LOG2E 1.4426950408889634f

__device__ __forceinline__ float b2f(u16 u) {
    union { unsigned int i; float f; } x; x.i = ((unsigned int)u) << 16; return x.f;
}
__device__ __forceinline__ u16 f2b(float f) {
    union { float f; unsigned int i; } x; x.f = f;
    unsigned int r = x.i + 0x7FFFu + ((x.i >> 16) & 1u);   // RNE
    return (u16)(r >> 16);
}
__device__ __forceinline__ u32 pk2(float a, float b) {
    union { __hip_bfloat162 h; u32 u; } p;
    p.h = __float22bfloat162_rn(float2{a, b});
    return p.u;
}
__device__ __forceinline__ float fexp2(float x) {   // raw v_exp_f32 (log2 domain)
    return __builtin_amdgcn_exp2f(x);
}
struct alignas(8) us4 { u16 x, y, z, w; };

__device__ __forceinline__ void gload16(const void* g, void* l) {
    __builtin_amdgcn_global_load_lds(
        (const __attribute__((address_space(1))) void*)g,
        (__attribute__((address_space(3))) void*)l, 16, 0, 0);
}

// -------- merged prologue: weight transposes + conv-weight fold + bias tables --------
__global__ __launch_bounds__(256) void prep_all(
    const float* __restrict__ w0, const float* __restrict__ w1,
    const float* __restrict__ w2, const float* __restrict__ w3, u16* __restrict__ wTbase,
    const float* __restrict__ cw0, const float* __restrict__ g0, const float* __restrict__ bb0,
    const float* __restrict__ m0, const float* __restrict__ v0,
    const float* __restrict__ cw1, const float* __restrict__ g1, const float* __restrict__ bb1,
    const float* __restrict__ m1, const float* __restrict__ v1,
    const float* __restrict__ cw2, const float* __restrict__ g2, const float* __restrict__ bb2,
    const float* __restrict__ m2, const float* __restrict__ v2,
    float* __restrict__ cwfb, float* __restrict__ shb,
    const float* __restrict__ rpb_t, const float* __restrict__ tt,
    const float* __restrict__ tg, u16* __restrict__ btab,
    const float* __restrict__ rpb_m, u16* __restrict__ mtab) {
    __shared__ float t[32][33];
    const int id = blockIdx.x, tid = threadIdx.x;
    if (id < 1024) {
        const int z = id >> 8, rem = id & 255;
        const int bx = rem & 15, by = rem >> 4;
        const float* W = z == 0 ? w0 : z == 1 ? w1 : z == 2 ? w2 : w3;
        u16* WT = wTbase + (size_t)z * 262144;
        const int tx = tid & 31, ty = tid >> 5;
        for (int i = ty; i < 32; i += 8)
            t[i][tx] = W[(size_t)(by * 32 + i) * 512 + bx * 32 + tx];
        __syncthreads();
        for (int i = ty; i < 32; i += 8)
            WT[(size_t)(bx * 32 + i) * 512 + by * 32 + tx] = f2b(t[tx][i]);
    } else if (id < 1051) {
        const int rem = id - 1024;
        const int tap = rem % 9, br = rem / 9;
        const float* cw = br == 0 ? cw0 : br == 1 ? cw1 : cw2;
        const float* g  = br == 0 ? g0  : br == 1 ? g1  : g2;
        const float* bb = br == 0 ? bb0 : br == 1 ? bb1 : bb2;
        const float* m  = br == 0 ? m0  : br == 1 ? m1  : m2;
        const float* v  = br == 0 ? v0  : br == 1 ? v1  : v2;
        for (int c = tid; c < DM; c += 256) {
            const float inv = g[c] * rsqrtf(v[c] + 1e-5f);
            cwfb[(br * 9 + tap) * DM + c] = cw[c * 9 + tap] * inv;
            if (tap == 0) shb[br * DM + c] = bb[c] - m[c] * inv;
        }
    } else if (id < 4923) {
        const int rem = id - 1051;
        const int h = rem / NTGT, q = rem % NTGT;
        const int qh = q / 22, qw = q % 22;
        const float tgv = tg[h * NTGT + q];
        for (int k = tid; k < KPAD; k += 256) {
            float val;
            if (k < NTMP) val = (tt[h * NTMP + k] + tgv) * LOG2E;
            else if (k < NTOK) {
                const int kj = k - NTMP, kh = kj / 22, kw = kj % 22;
                val = rpb_t[((qh - kh + 21) * 43 + (qw - kw + 21)) * MH + h] * LOG2E;
            } else val = -1e30f;
            btab[((size_t)(h * NTGT + q)) * KPAD + k] = f2b(val);
        }
    } else {
        const int q = id - 4923, k = tid;
        const int qh = q >> 4, qw = q & 15, kh = k >> 4, kw = k & 15;
        mtab[q * 256 + k] = f2b(rpb_m[(qh - kh + 15) * 31 + (qw - kw + 15)] * LOG2E);
    }
}

// ---------------- fused depthwise 3x3 conv (+folded BN) for q,k,v ----------------
__global__ __launch_bounds__(256) void conv_bn3(
    const float* __restrict__ x,
    const float* __restrict__ cwfb, const float* __restrict__ shb,
    u16* __restrict__ o0, u16* __restrict__ o1, u16* __restrict__ o2) {
    const int bn = blockIdx.x * 2 + (threadIdx.x >> 7);
    const int c = (threadIdx.x & 127) * 4;
    const int b = bn / NTOK, n = bn % NTOK;
    const bool tmp = n < NTMP;
    const int L = tmp ? 16 : 22, base = tmp ? 0 : NTMP, p = n - base;
    const int ph = p / L, pw = p % L;
    float4 xv[9];
#pragma unroll
    for (int tap = 0; tap < 9; ++tap) {
        const int dh = tap / 3 - 1, dw = tap % 3 - 1;
        const int h2 = ph + dh, w2 = pw + dw;
        const bool ok = (h2 >= 0 && h2 < L && w2 >= 0 && w2 < L);
        xv[tap] = ok ? *(const float4*)(x + (size_t)(b * NTOK + base + h2 * L + w2) * DM + c)
                     : float4{0.f, 0.f, 0.f, 0.f};
    }
    const size_t o = (size_t)bn * DM + c;
    u16* out[3] = {o0, o1, o2};
#pragma unroll
    for (int br = 0; br < 3; ++br) {
        float4 acc = *(const float4*)(shb + br * DM + c);
#pragma unroll
        for (int tap = 0; tap < 9; ++tap) {
            const float4 wv = *(const float4*)(cwfb + (br * 9 + tap) * DM + c);
            acc.x = fmaf(wv.x, xv[tap].x, acc.x);
            acc.y = fmaf(wv.y, xv[tap].y, acc.y);
            acc.z = fmaf(wv.z, xv[tap].z, acc.z);
            acc.w = fmaf(wv.w, xv[tap].w, acc.w);
        }
        us4 r;
        r.x = f2b(acc.x); r.y = f2b(acc.y); r.z = f2b(acc.z); r.w = f2b(acc.w);
        *(us4*)(out[br] + o) = r;
    }
}

// ---- GEMM 64x128 tile, 4-buffer prefetch-3, counted vmcnt + raw s_barrier ----
#define STAGE(bf, kk) do {                                                           \
    gload16(asrc + (kk) * 32, &As[bf][w * 512]);                                     \
    gload16(bsrc0 + (kk) * 32, &Bs[bf][w * 1024]);                                   \
    gload16(bsrc1 + (kk) * 32, &Bs[bf][w * 1024 + 512]);                             \
} while (0)

#define GEMM_BODY(A, BT)                                                             \
    const int tid = threadIdx.x;                                                     \
    const int lane = tid & 63, w = tid >> 6;                                         \
    const int lr = lane & 15, lg = lane >> 4;                                        \
    const int wm = (w >> 1) * 32, wn = (w & 1) * 64;                                 \
    const int srow4 = lane >> 2;                                                     \
    const int sc = (lane & 3) ^ ((srow4 & 3) ^ ((srow4 >> 2) & 3));                  \
    const int flr = (lr & 3) ^ ((lr >> 2) & 3);                                      \
    const u16* asrc  = A  + (size_t)(gm0 + w * 16 + srow4) * 512 + sc * 8;           \
    const u16* bsrc0 = BT + (size_t)(gn0 + w * 32 + srow4) * 512 + sc * 8;           \
    const u16* bsrc1 = BT + (size_t)(gn0 + w * 32 + 16 + srow4) * 512 + sc * 8;      \
    f32x4 acc[2][4] = {};                                                            \
    STAGE(0, 0); STAGE(1, 1); STAGE(2, 2);                                           \
    _Pragma("unroll")                                                                \
    for (int kt = 0; kt < 16; ++kt) {                                                \
        const int cur = kt & 3;                                                      \
        if (kt < 13) {                                                               \
            STAGE((kt + 3) & 3, kt + 3);                                             \
            asm volatile("s_waitcnt vmcnt(9)" ::: "memory");                         \
        } else if (kt == 13) {                                                       \
            asm volatile("s_waitcnt vmcnt(6)" ::: "memory");                         \
        } else if (kt == 14) {                                                       \
            asm volatile("s_waitcnt vmcnt(3)" ::: "memory");                         \
        } else {                                                                     \
            asm volatile("s_waitcnt vmcnt(0)" ::: "memory");                         \
        }                                                                            \
        __builtin_amdgcn_s_barrier();                                                \
        asm volatile("" ::: "memory");                                               \
        short8 af[2], bfr[4];                                                        \
        _Pragma("unroll")                                                            \
        for (int i = 0; i < 2; ++i)                                                  \
            af[i] = *(const short8*)&As[cur][(wm + i * 16 + lr) * 32 + (lg ^ flr) * 8]; \
        _Pragma("unroll")                                                            \
        for (int j = 0; j < 4; ++j)                                                  \
            bfr[j] = *(const short8*)&Bs[cur][(wn + j * 16 + lr) * 32 + (lg ^ flr) * 8]; \
        _Pragma("unroll")                                                            \
        for (int i = 0; i < 2; ++i)                                                  \
            _Pragma("unroll")                                                        \
            for (int j = 0; j < 4; ++j)                                              \
                acc[i][j] = __builtin_amdgcn_mfma_f32_16x16x32_bf16(af[i], bfr[j], acc[i][j], 0, 0, 0); \
        asm volatile("" ::: "memory");                                               \
        __builtin_amdgcn_s_barrier();                                                \
    }

// Q/K/V GEMMs: z = blockIdx.z + zbase selects branch. z==2 writes vbT layout.
__global__ __launch_bounds__(256) void gemm_qkv(
    const u16* __restrict__ Aq, const u16* __restrict__ Ak, const u16* __restrict__ Av,
    const u16* __restrict__ wTb, const float* __restrict__ bq,
    const float* __restrict__ bk, const float* __restrict__ bv,
    u16* __restrict__ qout, u16* __restrict__ kout, u16* __restrict__ vbT, int zbase) {
    __shared__ u16 As[4][2048];
    __shared__ u16 Bs[4][4096];
    const int gm0 = blockIdx.x * 64, gn0 = blockIdx.y * 128;
    const int z = blockIdx.z + zbase;
    const u16* A = z == 0 ? Aq : z == 1 ? Ak : Av;
    const u16* BT = wTb + (size_t)z * 262144;
    const float* bias = z == 0 ? bq : z == 1 ? bk : bv;
    GEMM_BODY(A, BT)
    u16* lin = z == 0 ? qout : kout;
#pragma unroll
    for (int i = 0; i < 2; ++i)
#pragma unroll
        for (int j = 0; j < 4; ++j) {
            const int gc = gn0 + wn + j * 16 + lr;
            const float bvl = bias[gc];
#pragma unroll
            for (int r = 0; r < 4; ++r) {
                const int gr = gm0 + wm + i * 16 + lg * 4 + r;
                const float val = acc[i][j][r] + bvl;
                if (z == 2) {
                    const int b2 = gr / NTOK, k = gr - b2 * NTOK;
                    const int hh = gc >> 6, d = gc & 63;
                    vbT[((size_t)(b2 * MH + hh) * 64 + d) * KPAD + k] = f2b(val);
                } else {
                    lin[(size_t)gr * 512 + gc] = f2b(val);
                }
            }
        }
}

// final projection GEMM: f32 out
__global__ __launch_bounds__(256) void gemm_out(const u16* __restrict__ Ain,
                                                const u16* __restrict__ BTin,
                                                const float* __restrict__ bias,
                                                float* __restrict__ C) {
    __shared__ u16 As[4][2048];
    __shared__ u16 Bs[4][4096];
    const int gm0 = blockIdx.x * 64, gn0 = blockIdx.y * 128;
    GEMM_BODY(Ain, BTin)
#pragma unroll
    for (int i = 0; i < 2; ++i)
#pragma unroll
        for (int j = 0; j < 4; ++j) {
            const int gc = gn0 + wn + j * 16 + lr;
            const float bvl = bias[gc];
#pragma unroll
            for (int r = 0; r < 4; ++r) {
                const int gr = gm0 + wm + i * 16 + lg * 4 + r;
                C[(size_t)gr * 512 + gc] = acc[i][j][r] + bvl;
            }
        }
}

// ---------------- merged MFMA flash attention: 128 q-rows/block, O^T form ----------------
// 3 LDS buffers (32 KB ceiling), K/V stage distance-1, ONE barrier per chunk,
// PLUS bias register prefetch distance-1 (no LDS cost — isolated test of R26's (b)).
// Per-iter issue order: B(kc+1)[4 loads], S(kc+1)[2 gload16]. FIFO at wait:
// need B(kc)+S(kc) (issued last iter) complete; 6 newer allowed -> vmcnt(6).
// Prologue: S(0), B(0) -> at kc=0 outstanding S0(2)+B0(4)+B1(4)+S1(2)=12, oldest 6 drain.
__global__ __launch_bounds__(256) void attn_all(const u16* __restrict__ qb,
                                                const u16* __restrict__ kb,
                                                const u16* __restrict__ vbT,
                                                const u16* __restrict__ btab,
                                                const u16* __restrict__ mtab,
                                                u16* __restrict__ attb) {
    __shared__ u16 Ks[3][32][64];       // keys x d  (8-chunk swizzle, 128B rows)
    __shared__ u16 VTs[3][64][32];      // d x keys  (4-chunk swizzle incl. >>2 term)
    __shared__ u16 Pb[2][4][16][32];    // per-(qtile,wave) P^T round-trip

    // XCD-bijective remap: 768 blocks % 8 == 0; 96/XCD = 16 (h,b) pairs x 6 tiles
    int wg = blockIdx.x + 6 * (blockIdx.y + 8 * blockIdx.z);
    wg = (wg & 7) * 96 + (wg >> 3);
    const int bx = wg % 6;
    const int hb = wg / 6;
    const int h = hb & 7, b = hb >> 3;

    const bool tgt = bx < 4;
    const int q0 = (tgt ? bx : bx - 4) * 128;
    const int NKr = tgt ? NTOK : NTMP;
    const int NCH = tgt ? 24 : 8;
    const int QTOT = tgt ? NTGT : NTMP;
    const int QOFF = tgt ? NTMP : 0;
    const int TK = tgt ? KPAD : 256;
    const int tid = threadIdx.x;
    const int w = tid >> 6, lane = tid & 63;
    const int lq = lane & 15, lg = lane >> 4;
    const int fq = (lq & 3) ^ ((lq >> 2) & 3);      // phase-safe 4-chunk swizzle
    const size_t brow = (size_t)b * NTOK;
    const float SCL = 0.125f * LOG2E;

    int qA = q0 + w * 16 + lq;       if (qA > QTOT - 1) qA = QTOT - 1;
    int qB = q0 + 64 + w * 16 + lq;  if (qB > QTOT - 1) qB = QTOT - 1;
    const u16* tbase = tgt ? (btab + (size_t)h * NTGT * KPAD) : mtab;
    const u16* trowA = tbase + (size_t)qA * TK;
    const u16* trowB = tbase + (size_t)qB * TK;

    short8 qfA[2], qfB[2];
#pragma unroll
    for (int dc = 0; dc < 2; ++dc) {
        qfA[dc] = *(const short8*)(qb + (brow + QOFF + qA) * DM + h * 64 + dc * 32 + lg * 8);
        qfB[dc] = *(const short8*)(qb + (brow + QOFF + qB) * DM + h * 64 + dc * 32 + lg * 8);
    }

    // staging: gload_lds, lane-linear LDS dest; source chunk pre-XORed with row fn
    const int krow = tid >> 3, ksc = tid & 7;
    const int vrow = tid >> 2, vsc = tid & 3;
    const int fv = (vrow & 3) ^ ((vrow >> 2) & 3);
    const size_t vbase = (size_t)(b * MH + h) * 64 * KPAD;
    const u16* kptr2 = kb + brow * DM + h * 64 + (ksc ^ (krow & 7)) * 8;
    const u16* vptr2 = vbT + vbase + (size_t)vrow * KPAD + (vsc ^ fv) * 8;
    const int NKm1 = NKr - 1;

    float mrunA = -1e30f, lrunA = 0.f, mrunB = -1e30f, lrunB = 0.f;
    f32x4 oTA[4] = {}, oTB[4] = {};

    // prologue: S(0) then B(0) (FIFO: S0 oldest)
    {
        const int keyc = krow < NKm1 ? krow : NKm1;
        gload16(kptr2 + (size_t)keyc * DM, &Ks[0][w * 8][0]);
        gload16(vptr2, &VTs[0][w * 16][0]);
    }
    us4 bcA0 = *(const us4*)(trowA + lg * 4);
    us4 bcA1 = *(const us4*)(trowA + 16 + lg * 4);
    us4 bcB0 = *(const us4*)(trowB + lg * 4);
    us4 bcB1 = *(const us4*)(trowB + 16 + lg * 4);

    int cur = 0;
    for (int kc = 0; kc < NCH; ++kc) {
        const int nxt = cur + 1 < 3 ? cur + 1 : 0;
        const bool more = (kc + 1 < NCH);
        us4 bnA0 = {0,0,0,0}, bnA1 = {0,0,0,0}, bnB0 = {0,0,0,0}, bnB1 = {0,0,0,0};
        if (more) {
            // bias prefetch for NEXT chunk (distance-1)
            bnA0 = *(const us4*)(trowA + (kc + 1) * 32 + lg * 4);
            bnA1 = *(const us4*)(trowA + (kc + 1) * 32 + 16 + lg * 4);
            bnB0 = *(const us4*)(trowB + (kc + 1) * 32 + lg * 4);
            bnB1 = *(const us4*)(trowB + (kc + 1) * 32 + 16 + lg * 4);
            // K/V staging for NEXT chunk (distance-1)
            const int key = (kc + 1) * 32 + krow;
            const int keyc = key < NKm1 ? key : NKm1;
            gload16(kptr2 + (size_t)keyc * DM, &Ks[nxt][w * 8][0]);
            gload16(vptr2 + (kc + 1) * 32, &VTs[nxt][w * 16][0]);
            asm volatile("s_waitcnt vmcnt(6)" ::: "memory");   // B(kc)+S(kc) complete
        } else {
            asm volatile("s_waitcnt vmcnt(0)" ::: "memory");
        }
        __builtin_amdgcn_s_barrier();
        asm volatile("" ::: "memory");

        // ---- S^T for both q-tiles: K-frags read once ----
        f32x4 sA0 = {}, sA1 = {}, sB0 = {}, sB1 = {};
        __builtin_amdgcn_s_setprio(1);
#pragma unroll
        for (int dc = 0; dc < 2; ++dc) {
            short8 a0 = *(const short8*)&Ks[cur][lq][((dc * 4 + lg) ^ (lq & 7)) * 8];
            short8 a1 = *(const short8*)&Ks[cur][16 + lq][((dc * 4 + lg) ^ (lq & 7)) * 8];
            sA0 = __builtin_amdgcn_mfma_f32_16x16x32_bf16(a0, qfA[dc], sA0, 0, 0, 0);
            sB0 = __builtin_amdgcn_mfma_f32_16x16x32_bf16(a0, qfB[dc], sB0, 0, 0, 0);
            sA1 = __builtin_amdgcn_mfma_f32_16x16x32_bf16(a1, qfA[dc], sA1, 0, 0, 0);
            sB1 = __builtin_amdgcn_mfma_f32_16x16x32_bf16(a1, qfB[dc], sB1, 0, 0, 0);
        }
        __builtin_amdgcn_s_setprio(0);

        // ---- softmax tile A ----
        {
            float sv[8];
            sv[0] = fmaf(sA0[0], SCL, b2f(bcA0.x)); sv[1] = fmaf(sA0[1], SCL, b2f(bcA0.y));
            sv[2] = fmaf(sA0[2], SCL, b2f(bcA0.z)); sv[3] = fmaf(sA0[3], SCL, b2f(bcA0.w));
            sv[4] = fmaf(sA1[0], SCL, b2f(bcA1.x)); sv[5] = fmaf(sA1[1], SCL, b2f(bcA1.y));
            sv[6] = fmaf(sA1[2], SCL, b2f(bcA1.z)); sv[7] = fmaf(sA1[3], SCL, b2f(bcA1.w));
            float cm = sv[0];
#pragma unroll
            for (int i = 1; i < 8; ++i) cm = fmaxf(cm, sv[i]);
            cm = fmaxf(cm, __shfl_xor(cm, 16));
            cm = fmaxf(cm, __shfl_xor(cm, 32));
            if (!__all(cm <= mrunA)) {
                const float mnew = fmaxf(mrunA, cm);
                const float alpha = fexp2(mrunA - mnew);
#pragma unroll
                for (int t = 0; t < 4; ++t)
#pragma unroll
                    for (int r = 0; r < 4; ++r) oTA[t][r] *= alpha;
                lrunA *= alpha;
                mrunA = mnew;
            }
            float pv[8], psum = 0.f;
#pragma unroll
            for (int i = 0; i < 8; ++i) { pv[i] = fexp2(sv[i] - mrunA); psum += pv[i]; }
            const int c0 = (((lg >> 1) ^ fq) & 3) * 8 + (lg & 1) * 4;
            const int c1 = (((2 + (lg >> 1)) ^ fq) & 3) * 8 + (lg & 1) * 4;
            *(uint2*)&Pb[0][w][lq][c0] = uint2{pk2(pv[0], pv[1]), pk2(pv[2], pv[3])};
            *(uint2*)&Pb[0][w][lq][c1] = uint2{pk2(pv[4], pv[5]), pk2(pv[6], pv[7])};
            psum += __shfl_xor(psum, 16);
            psum += __shfl_xor(psum, 32);
            lrunA += psum;
        }
        // ---- softmax tile B ----
        {
            float sv[8];
            sv[0] = fmaf(sB0[0], SCL, b2f(bcB0.x)); sv[1] = fmaf(sB0[1], SCL, b2f(bcB0.y));
            sv[2] = fmaf(sB0[2], SCL, b2f(bcB0.z)); sv[3] = fmaf(sB0[3], SCL, b2f(bcB0.w));
            sv[4] = fmaf(sB1[0], SCL, b2f(bcB1.x)); sv[5] = fmaf(sB1[1], SCL, b2f(bcB1.y));
            sv[6] = fmaf(sB1[2], SCL, b2f(bcB1.z)); sv[7] = fmaf(sB1[3], SCL, b2f(bcB1.w));
            float cm = sv[0];
#pragma unroll
            for (int i = 1; i < 8; ++i) cm = fmaxf(cm, sv[i]);
            cm = fmaxf(cm, __shfl_xor(cm, 16));
            cm = fmaxf(cm, __shfl_xor(cm, 32));
            if (!__all(cm <= mrunB)) {
                const float mnew = fmaxf(mrunB, cm);
                const float alpha = fexp2(mrunB - mnew);
#pragma unroll
                for (int t = 0; t < 4; ++t)
#pragma unroll
                    for (int r = 0; r < 4; ++r) oTB[t][r] *= alpha;
                lrunB *= alpha;
                mrunB = mnew;
            }
            float pv[8], psum = 0.f;
#pragma unroll
            for (int i = 0; i < 8; ++i) { pv[i] = fexp2(sv[i] - mrunB); psum += pv[i]; }
            const int c0 = (((lg >> 1) ^ fq) & 3) * 8 + (lg & 1) * 4;
            const int c1 = (((2 + (lg >> 1)) ^ fq) & 3) * 8 + (lg & 1) * 4;
            *(uint2*)&Pb[1][w][lq][c0] = uint2{pk2(pv[0], pv[1]), pk2(pv[2], pv[3])};
            *(uint2*)&Pb[1][w][lq][c1] = uint2{pk2(pv[4], pv[5]), pk2(pv[6], pv[7])};
            psum += __shfl_xor(psum, 16);
            psum += __shfl_xor(psum, 32);
            lrunB += psum;
        }

        asm volatile("s_waitcnt lgkmcnt(0)" ::: "memory");

        // ---- PV both tiles: V-frags read once ----
        short8 pfA = *(const short8*)&Pb[0][w][lq][((lg ^ fq) & 3) * 8];
        short8 pfB = *(const short8*)&Pb[1][w][lq][((lg ^ fq) & 3) * 8];
        __builtin_amdgcn_s_setprio(1);
#pragma unroll
        for (int t = 0; t < 4; ++t) {
            short8 vf = *(const short8*)&VTs[cur][t * 16 + lq][((lg ^ fq) & 3) * 8];
            oTA[t] = __builtin_amdgcn_mfma_f32_16x16x32_bf16(vf, pfA, oTA[t], 0, 0, 0);
            oTB[t] = __builtin_amdgcn_mfma_f32_16x16x32_bf16(vf, pfB, oTB[t], 0, 0, 0);
        }
        __builtin_amdgcn_s_setprio(0);

        bcA0 = bnA0; bcA1 = bnA1; bcB0 = bnB0; bcB1 = bnB1;
        cur = nxt;
    }

    // epilogue: O[q][d] stores, q lane-local
    {
        const float linv = 1.f / lrunA;
        const int qrow = q0 + w * 16 + lq;
        if (qrow < QTOT) {
            u16* op = attb + (brow + QOFF + qrow) * DM + h * 64;
#pragma unroll
            for (int t = 0; t < 4; ++t)
                *(uint2*)(op + t * 16 + lg * 4) =
                    uint2{pk2(oTA[t][0] * linv, oTA[t][1] * linv),
                          pk2(oTA[t][2] * linv, oTA[t][3] * linv)};
        }
    }
    {
        const float linv = 1.f / lrunB;
        const int qrow = q0 + 64 + w * 16 + lq;
        if (qrow < QTOT) {
            u16* op = attb + (brow + QOFF + qrow) * DM + h * 64;
#pragma unroll
            for (int t = 0; t < 4; ++t)
                *(uint2*)(op + t * 16 + lg * 4) =
                    uint2{pk2(oTB[t][0] * linv, oTB[t][1] * linv),
                          pk2(oTB[t][2] * linv, oTB[t][3] * linv)};
        }
    }
}

// ---------------- launch ----------------
extern "C" void kernel_launch(void* const* d_in, const int* in_sizes, int n_in,
                              void* d_out, int out_size, void* d_ws, size_t ws_size,
                              hipStream_t stream) {
    const float* x = (const float*)d_in[0];
    const float* convw[3] = {(const float*)d_in[1], (const float*)d_in[6], (const float*)d_in[11]};
    const float* bng[3]   = {(const float*)d_in[2], (const float*)d_in[7], (const float*)d_in[12]};
    const float* bnb[3]   = {(const float*)d_in[3], (const float*)d_in[8], (const float*)d_in[13]};
    const float* bnm[3]   = {(const float*)d_in[4], (const float*)d_in[9], (const float*)d_in[14]};
    const float* bnv[3]   = {(const float*)d_in[5], (const float*)d_in[10], (const float*)d_in[15]};
    const float* w[4]     = {(const float*)d_in[16], (const float*)d_in[18], (const float*)d_in[20], (const float*)d_in[22]};
    const float* bias[4]  = {(const float*)d_in[17], (const float*)d_in[19], (const float*)d_in[21], (const float*)d_in[23]};
    const float* rpb_t = (const float*)d_in[24];
    const float* rpb_m = (const float*)d_in[25];
    const float* tt    = (const float*)d_in[26];
    const float* tg    = (const float*)d_in[27];

    char* p = (char*)d_ws;
    auto alloc = [&](size_t n) { char* r = p; p += (n + 255) & ~(size_t)255; return r; };
    const size_t SEQ = (size_t)MROWS * DM * 2;   // 12,124,160 B
    u16* wTb  = (u16*)alloc(4 * 524288);
    u16* cbq  = (u16*)alloc(SEQ);
    u16* cbk  = (u16*)alloc(SEQ);
    u16* cbv  = (u16*)alloc(SEQ);
    u16* kbuf = (u16*)alloc(SEQ);
    u16* vbT  = (u16*)alloc((size_t)16 * MH * 64 * KPAD * 2);   // 12,582,912
    u16* btab = (u16*)alloc((size_t)MH * NTGT * KPAD * 2);      // 5,947,392
    u16* mtab = (u16*)alloc(256 * 256 * 2);
    float* cwf = (float*)alloc(3 * 9 * DM * 4);
    float* shf = (float*)alloc(3 * DM * 4);
    const size_t used = (size_t)(p - (char*)d_ws);
    const bool merged = ws_size >= used + SEQ;
    u16* qbuf = merged ? (u16*)alloc(SEQ) : cbv;   // fallback aliases cbv
    u16* attb = cbq;   // cbq dead after Q-GEMM

    prep_all<<<5179, 256, 0, stream>>>(
        w[0], w[1], w[2], w[3], wTb,
        convw[0], bng[0], bnb[0], bnm[0], bnv[0],
        convw[1], bng[1], bnb[1], bnm[1], bnv[1],
        convw[2], bng[2], bnb[2], bnm[2], bnv[2], cwf, shf,
        rpb_t, tt, tg, btab, rpb_m, mtab);

    conv_bn3<<<MROWS / 2, 256, 0, stream>>>(x, cwf, shf, cbq, cbk, cbv);

    if (merged) {
        gemm_qkv<<<dim3(185, 4, 3), 256, 0, stream>>>(cbq, cbk, cbv, wTb,
                                                      bias[0], bias[1], bias[2],
                                                      qbuf, kbuf, vbT, 0);
    } else {
        // V first (reads cbv), then Q+K (Q writes qbuf==cbv) — stream order keeps it safe
        gemm_qkv<<<dim3(185, 4, 1), 256, 0, stream>>>(cbq, cbk, cbv, wTb,
                                                      bias[0], bias[1], bias[2],
                                                      qbuf, kbuf, vbT, 2);
        gemm_qkv<<<dim3(185, 4, 2), 256, 0, stream>>>(cbq, cbk, cbv, wTb,
                                                      bias[0], bias[1], bias[2],
                                                      qbuf, kbuf, vbT, 0);
    }

    attn_all<<<dim3(6, 8, 16), 256, 0, stream>>>(qbuf, kbuf, vbT, btab, mtab, attb);

    gemm_out<<<dim3(185, 4), 256, 0, stream>>>(attb, wTb + 3 * 262144, bias[3], (float*)d_out);
}